// Round 1
// baseline (2606.110 us; speedup 1.0000x reference)
//
#include <hip/hip_runtime.h>
#include <hip/hip_bf16.h>
#include <cstdint>
#include <cstddef>

typedef _Float16 half8 __attribute__((ext_vector_type(8)));
typedef _Float16 half4 __attribute__((ext_vector_type(4)));
typedef float floatx4 __attribute__((ext_vector_type(4)));

#define B_ 256
#define T_ 168
#define H_ 1024
#define WS_ 64
#define LAG_ 168
#define LAT_ 128

// ---------------- fp32 -> fp16 conversion (vectorized x4) ----------------
__global__ void cvt_f32_f16_v4(const float4* __restrict__ src, half4* __restrict__ dst, int n4) {
    int i = blockIdx.x * blockDim.x + threadIdx.x;
    if (i < n4) {
        float4 v = src[i];
        half4 o;
        o[0] = (_Float16)v.x; o[1] = (_Float16)v.y;
        o[2] = (_Float16)v.z; o[3] = (_Float16)v.w;
        dst[i] = o;
    }
}

// ---------------- encoder layers 1,2: leaky(in @ W^T + b) ----------------
// grid = B_ rows, block = out_features (64 or 128)
__global__ void enc12(const float* __restrict__ in, const float* __restrict__ W,
                      const float* __restrict__ bias, float* __restrict__ outb, int infeat) {
    int r = blockIdx.x, j = threadIdx.x;
    const float* row = in + (size_t)r * infeat;
    const float* w   = W  + (size_t)j * infeat;
    float s = bias[j];
    for (int k = 0; k < infeat; ++k) s += row[k] * w[k];
    outb[(size_t)r * blockDim.x + j] = (s >= 0.f) ? s : 0.01f * s;
}

// ---------------- encoder layer 3: h0 = h2 @ W3^T + b3 (no act) ----------------
__global__ void enc3(const float* __restrict__ h2, const float* __restrict__ W3,
                     const float* __restrict__ b3, float* __restrict__ hprev32,
                     _Float16* __restrict__ h0f16) {
    __shared__ float s[LAT_];
    int r = blockIdx.x;
    if (threadIdx.x < LAT_) s[threadIdx.x] = h2[(size_t)r * LAT_ + threadIdx.x];
    __syncthreads();
    for (int j = threadIdx.x; j < H_; j += 256) {
        const float* w = W3 + (size_t)j * LAT_;
        float acc = b3[j];
        #pragma unroll 8
        for (int k = 0; k < LAT_; ++k) acc += s[k] * w[k];
        hprev32[(size_t)r * H_ + j] = acc;
        h0f16[(size_t)r * H_ + j]   = (_Float16)acc;
    }
}

// ---------------- GRU step ----------------
// grid: 256 WGs = 4 row-blocks (64 rows) x 64 hidden-slices (16 cols, all 3 gates)
// block: 256 threads = 4 waves; wave w handles rows [pi*64 + w*16, +16)
__global__ __launch_bounds__(256) void gru_step(
    const _Float16* __restrict__ hsrc16,   // [B,H] prev h (fp16)
    _Float16* __restrict__ hdst16,         // [B,H] new h (fp16)
    float* __restrict__ hprev32,           // [B,H] fp32 master h (in/out)
    const _Float16* __restrict__ whh16,    // [3H,H]
    const _Float16* __restrict__ wih16,    // [3H,WS]
    const _Float16* __restrict__ x16,      // [T,B,WS]
    const float* __restrict__ bih,         // [3H]
    const float* __restrict__ bhh,         // [3H]
    const float* __restrict__ wo,          // [H]
    float* __restrict__ partials,          // [T,B,64]
    int t)
{
    constexpr int KC  = 512;      // K-chunk of Whh staged in LDS
    constexpr int LDW = KC + 8;   // fp16 stride (+8 pad -> balanced b128 bank groups)
    __shared__ __align__(16) _Float16 Bs[48 * LDW];   // 49,920 B

    const int tid  = threadIdx.x;
    const int wave = tid >> 6;
    const int lane = tid & 63;
    const int m16  = lane & 15;   // A row within 16-tile / C col
    const int quad = lane >> 4;   // 0..3
    const int pi   = blockIdx.x & 3;    // row block
    const int qi   = blockIdx.x >> 2;   // hidden slice

    floatx4 acc_gh[3], acc_gi[3];
    #pragma unroll
    for (int g = 0; g < 3; ++g) {
        acc_gh[g] = (floatx4){0.f, 0.f, 0.f, 0.f};
        acc_gi[g] = (floatx4){0.f, 0.f, 0.f, 0.f};
    }

    const int rowbase = pi * 64 + wave * 16;
    const _Float16* arow = hsrc16 + (size_t)(rowbase + m16) * H_;

    // ---- gh = h @ Whh^T over two K-chunks ----
    for (int c = 0; c < 2; ++c) {
        // stage Whh chunk: 48 gate-rows x 512 k  (3072 uint4, 12 per thread)
        for (int u = tid; u < 3072; u += 256) {
            int rl = u >> 6;          // 0..47  (gate*16 + local col)
            int cu = u & 63;          // uint4 within row
            int grow = (rl >> 4) * H_ + qi * 16 + (rl & 15);
            const uint4* gp = (const uint4*)(whh16 + (size_t)grow * H_ + c * KC + cu * 8);
            *(uint4*)(&Bs[rl * LDW + cu * 8]) = *gp;
        }
        __syncthreads();
        #pragma unroll 4
        for (int kk = 0; kk < 16; ++kk) {
            int klocal = kk * 32 + quad * 8;
            half8 a = *(const half8*)(arow + c * KC + klocal);
            #pragma unroll
            for (int g = 0; g < 3; ++g) {
                half8 b = *(const half8*)(&Bs[(g * 16 + m16) * LDW + klocal]);
                acc_gh[g] = __builtin_amdgcn_mfma_f32_16x16x32_f16(a, b, acc_gh[g], 0, 0, 0);
            }
        }
        __syncthreads();
    }

    // ---- gi = x_t @ Wih^T (K=64), operands direct from global ----
    const _Float16* xrow = x16 + ((size_t)t * B_ + rowbase + m16) * WS_;
    #pragma unroll
    for (int kk = 0; kk < 2; ++kk) {
        int kg = kk * 32 + quad * 8;
        half8 a = *(const half8*)(xrow + kg);
        #pragma unroll
        for (int g = 0; g < 3; ++g) {
            half8 b = *(const half8*)(wih16 + (size_t)((g << 10) + qi * 16 + m16) * WS_ + kg);
            acc_gi[g] = __builtin_amdgcn_mfma_f32_16x16x32_f16(a, b, acc_gi[g], 0, 0, 0);
        }
    }

    // ---- gates + h update (C layout: col = lane&15, row = quad*4 + i) ----
    const int jj = qi * 16 + m16;
    const float b_ir = bih[jj],        b_hr = bhh[jj];
    const float b_iz = bih[H_ + jj],   b_hz = bhh[H_ + jj];
    const float b_in = bih[2*H_ + jj], b_hn = bhh[2*H_ + jj];
    const float woj = wo[jj];

    float pv[4];
    #pragma unroll
    for (int i = 0; i < 4; ++i) {
        int rr = rowbase + quad * 4 + i;
        float ir = acc_gi[0][i] + b_ir, hr = acc_gh[0][i] + b_hr;
        float iz = acc_gi[1][i] + b_iz, hz = acc_gh[1][i] + b_hz;
        float in_ = acc_gi[2][i] + b_in, hn = acc_gh[2][i] + b_hn;
        float rg = 1.f / (1.f + __expf(-(ir + hr)));
        float zg = 1.f / (1.f + __expf(-(iz + hz)));
        float ng = tanhf(in_ + rg * hn);
        float hp = hprev32[(size_t)rr * H_ + jj];
        float hnew = (1.f - zg) * ng + zg * hp;
        hprev32[(size_t)rr * H_ + jj] = hnew;
        hdst16[(size_t)rr * H_ + jj]  = (_Float16)hnew;
        pv[i] = hnew * woj;
    }
    // reduce pred partial over the 16 cols of this slice (lanes differing in low 4 bits)
    #pragma unroll
    for (int m = 1; m < 16; m <<= 1) {
        #pragma unroll
        for (int i = 0; i < 4; ++i) pv[i] += __shfl_xor(pv[i], m);
    }
    if (m16 == 0) {
        #pragma unroll
        for (int i = 0; i < 4; ++i) {
            int rr = rowbase + quad * 4 + i;
            partials[((size_t)t * B_ + rr) * 64 + qi] = pv[i];
        }
    }
}

// ---------------- final: out[r,t] = sum_q partials[t,r,q] + bo ----------------
__global__ void out_reduce(const float* __restrict__ partials, const float* __restrict__ bo,
                           float* __restrict__ out) {
    int t = blockIdx.x, r = threadIdx.x;
    const float* p = partials + ((size_t)t * B_ + r) * 64;
    float s = 0.f;
    #pragma unroll
    for (int i = 0; i < 64; ++i) s += p[i];
    out[(size_t)r * T_ + t] = s + bo[0];
}

extern "C" void kernel_launch(void* const* d_in, const int* in_sizes, int n_in,
                              void* d_out, int out_size, void* d_ws, size_t ws_size,
                              hipStream_t stream) {
    const float* lag  = (const float*)d_in[0];
    const float* curr = (const float*)d_in[1];
    const float* W1   = (const float*)d_in[2];
    const float* b1   = (const float*)d_in[3];
    const float* W2   = (const float*)d_in[4];
    const float* b2   = (const float*)d_in[5];
    const float* W3   = (const float*)d_in[6];
    const float* b3   = (const float*)d_in[7];
    const float* Wih  = (const float*)d_in[8];
    const float* Whh  = (const float*)d_in[9];
    const float* bih  = (const float*)d_in[10];
    const float* bhh  = (const float*)d_in[11];
    const float* Wo   = (const float*)d_in[12];
    const float* bo   = (const float*)d_in[13];
    float* out = (float*)d_out;

    char* ws = (char*)d_ws;
    size_t off = 0;
    auto alloc = [&](size_t bytes) -> void* {
        void* p = ws + off;
        off += (bytes + 255) & ~(size_t)255;
        return p;
    };
    _Float16* whh16 = (_Float16*)alloc((size_t)3 * H_ * H_ * 2);
    _Float16* wih16 = (_Float16*)alloc((size_t)3 * H_ * WS_ * 2);
    _Float16* x16   = (_Float16*)alloc((size_t)T_ * B_ * WS_ * 2);
    _Float16* hbuf0 = (_Float16*)alloc((size_t)B_ * H_ * 2);
    _Float16* hbuf1 = (_Float16*)alloc((size_t)B_ * H_ * 2);
    float* hprev32  = (float*)alloc((size_t)B_ * H_ * 4);
    float* h1       = (float*)alloc((size_t)B_ * 64 * 4);
    float* h2       = (float*)alloc((size_t)B_ * LAT_ * 4);
    float* partials = (float*)alloc((size_t)T_ * B_ * 64 * 4);

    int n4;
    n4 = 3 * H_ * H_ / 4;
    cvt_f32_f16_v4<<<(n4 + 255) / 256, 256, 0, stream>>>((const float4*)Whh, (half4*)whh16, n4);
    n4 = 3 * H_ * WS_ / 4;
    cvt_f32_f16_v4<<<(n4 + 255) / 256, 256, 0, stream>>>((const float4*)Wih, (half4*)wih16, n4);
    n4 = T_ * B_ * WS_ / 4;
    cvt_f32_f16_v4<<<(n4 + 255) / 256, 256, 0, stream>>>((const float4*)curr, (half4*)x16, n4);

    enc12<<<B_, 64, 0, stream>>>(lag, W1, b1, h1, LAG_);
    enc12<<<B_, LAT_, 0, stream>>>(h1, W2, b2, h2, 64);
    enc3<<<B_, 256, 0, stream>>>(h2, W3, b3, hprev32, hbuf0);

    for (int t = 0; t < T_; ++t) {
        const _Float16* hs = (t & 1) ? hbuf1 : hbuf0;
        _Float16*       hd = (t & 1) ? hbuf0 : hbuf1;
        gru_step<<<256, 256, 0, stream>>>(hs, hd, hprev32, whh16, wih16, x16,
                                          bih, bhh, Wo, partials, t);
    }
    out_reduce<<<T_, B_, 0, stream>>>(partials, bo, out);
}